// Round 9
// baseline (118.683 us; speedup 1.0000x reference)
//
#include <hip/hip_runtime.h>

// Chamfer loss: pred (2048,8,3) vs gt (2048,8,3) fp32. N=16384 pts/side.
// out = mean(min_m d) + mean(min_n d); 8-corner group-mean == global mean.
//
// R12: R11 counters killed the spill theory (VGPR=32, no scratch traffic,
// VALUBusy 93%) -> kernel is VALU-ISSUE-bound on per-xt flush overhead:
// the 16-lane DPP row-flush ran every xt (16x/wave) for only 4 MFMAs of
// work (~20 VALU instr/MFMA), plus 8-way LDS bank conflicts (1M cyc) on
// the col*64B fragment stride. Structural inversion:
//  - wave holds A-frags (its 64 x-points) AND rmax[4] accumulators;
//    iterates y-tiles from LDS. rmax is lane-local across the WHOLE
//    y-loop -> DPP flush once per block (16x less flush VALU).
//  - steady-state: 4 v_max3 per MFMA (rmax 4 + cmax 4 per MFMA pair),
//    2 ds_read per 8 MFMAs.
//  - fragment arrays repacked kg-major (tile*1024 + kg*256 + col*16):
//    LDS frag reads land 2 lanes/bank (free, m136) -> conflicts ~0;
//    A-gather + staging become fully linear/coalesced.
//  - waves now share y and split x: cmax needs one cross-wave LDS
//    combine (colacc 2KB); rmax stores are direct (waves own disjoint x).
//  - verified bf16 3-way-split math BIT-IDENTICAL (absmax 0.0 since R5):
//    same K-slot order, same -2*max, fmax 0, sqrt, mean.
// Fixed per round: 268MB ws re-poison fill ~40us + ~10us launch gaps.

#define NPTS   16384
#define BLOCK  256            // 4 waves
#define XW     64             // x-points per wave (4 tiles, af in 16 VGPR)
#define XCH    256            // x-points per block
#define NXB    (NPTS / XCH)   // 64
#define YCH    128            // y-points per block (8 tiles, 8KB LDS)
#define NYC    (NPTS / YCH)   // 128
#define ONEBF  0x3F80         // bf16 1.0

// ws: [0,1MB) Ppa | [1,2MB) Pgb | [2MB,14MB) part[192][NPTS] f32
//   slices 0..127  = row partials (pred mins), id = yc
//   slices 128..191= col partials (gt mins),   id = 128+xb
#define WS_PGB  (1u << 20)
#define WS_PART (2u << 20)
#define NROWSL  NYC           // 128
#define NCOLSL  NXB           // 64

typedef __attribute__((ext_vector_type(8))) short bf16x8;
typedef __attribute__((ext_vector_type(4))) float f32x4;

__device__ inline unsigned short f2bf(float f) {  // fp32 -> bf16 RNE
    unsigned int u = __float_as_uint(f);
    return (unsigned short)((u + 0x7FFFu + ((u >> 16) & 1u)) >> 16);
}
__device__ inline float bf2f(unsigned short h) {
    return __uint_as_float((unsigned int)h << 16);
}
__device__ inline void split3(float v, unsigned short* s) {
    unsigned short h = f2bf(v);  float r = v - bf2f(h);
    unsigned short m = f2bf(r);  r -= bf2f(m);
    s[0] = h; s[1] = m; s[2] = f2bf(r);
}

// K-slot map (identical order on A and B rows => lane->K bijection cancels):
//   s=c*3+d, c<6: cross combos (i,j)=(h,h)(h,m)(m,h)(h,l)(m,m)(l,h)
//   s=18..20: a=split3(-|p|^2/2), b=1 ; s=21..23: a=1, b=split3(-|p|^2/2)
//   s=24..31: 0   => S[r][c] = x.y - |x|^2/2 - |y|^2/2 = -d2/2
__device__ inline void build_rows(const float p[3], unsigned short* a,
                                  unsigned short* b) {
    const int CI[6] = {0, 0, 1, 0, 1, 2};
    const int CJ[6] = {0, 1, 0, 2, 1, 0};
    unsigned short xs[3][3], nn[3], t[3];
#pragma unroll
    for (int d = 0; d < 3; ++d) {
        split3(p[d], t);
        xs[0][d] = t[0]; xs[1][d] = t[1]; xs[2][d] = t[2];
    }
    split3(-0.5f * (p[0]*p[0] + p[1]*p[1] + p[2]*p[2]), nn);
#pragma unroll
    for (int c = 0; c < 6; ++c)
#pragma unroll
        for (int d = 0; d < 3; ++d) {
            a[c*3+d] = xs[CI[c]][d];
            b[c*3+d] = xs[CJ[c]][d];
        }
#pragma unroll
    for (int k = 0; k < 3; ++k) {
        a[18+k] = nn[k];  b[18+k] = ONEBF;
        a[21+k] = ONEBF;  b[21+k] = nn[k];
    }
#pragma unroll
    for (int k = 24; k < 32; ++k) { a[k] = 0; b[k] = 0; }
}

// Fragment-swizzled store: point i, chunk kg -> uint4 slot
// (i/16)*64 + kg*16 + (i%16). Lane (col,kg) then reads its MFMA fragment
// at a 16B-linear-in-col address: 2 lanes/bank (conflict-free).
__device__ inline void store_row_swz(uint4* dst4, int i, const unsigned short* s) {
    unsigned int w[16];
#pragma unroll
    for (int k = 0; k < 16; ++k)
        w[k] = (unsigned int)s[2*k] | ((unsigned int)s[2*k+1] << 16);
    const int base = (i >> 4) * 64 + (i & 15);
#pragma unroll
    for (int kgc = 0; kgc < 4; ++kgc)
        dst4[base + kgc * 16] = make_uint4(w[4*kgc], w[4*kgc+1],
                                           w[4*kgc+2], w[4*kgc+3]);
}

__global__ __launch_bounds__(256) void pack_points(
        const float* __restrict__ pred, const float* __restrict__ gt,
        unsigned short* __restrict__ Ppa, unsigned short* __restrict__ Pgb,
        float* __restrict__ out) {
    const int i = blockIdx.x * 256 + threadIdx.x;
    if (i == 0) out[0] = 0.0f;  // replaces a memset dispatch
    if (i >= NPTS) return;
    float p[3] = {pred[3*i], pred[3*i+1], pred[3*i+2]};
    float q[3] = {gt[3*i],   gt[3*i+1],   gt[3*i+2]};
    unsigned short ra[32], rb[32];
    build_rows(p, ra, rb);
    store_row_swz(reinterpret_cast<uint4*>(Ppa), i, ra);  // pred = A (rows)
    build_rows(q, ra, rb);
    store_row_swz(reinterpret_cast<uint4*>(Pgb), i, rb);  // gt = B (cols)
}

// DPP rotate-max within 16-lane rows (VALU pipe; verified R6-R11).
template <int CTRL>
__device__ inline float rormax(float v) {
    int t = __builtin_amdgcn_update_dpp(0, __float_as_int(v), CTRL, 0xF, 0xF,
                                        false);
    return fmaxf(v, __int_as_float(t));
}

__global__ __launch_bounds__(BLOCK) void chamfer_bidi(
        const unsigned short* __restrict__ Ppa,
        const unsigned short* __restrict__ Pgb,
        float* __restrict__ part) {
    const int yc = blockIdx.x;   // fastest-varying -> XCD = yc % 8 (B pin)
    const int xb = blockIdx.y;
    const int tid = threadIdx.x;
    const int lane = tid & 63, w = tid >> 6;
    const int col = lane & 15, kg = lane >> 4;
    const int frag = kg * 16 + col;     // uint4 index of this lane's frag

    __shared__ uint4 Bsh[YCH * 4];      // 8 KB: 8 tiles x 64 uint4
    __shared__ float colacc[4][YCH];    // 2 KB

    // stage B-chunk: 2 x 16B per thread, fully linear (global AND LDS)
    {
        const uint4* bsrc = reinterpret_cast<const uint4*>(Pgb) + yc * (YCH * 4);
        Bsh[tid]       = bsrc[tid];
        Bsh[256 + tid] = bsrc[256 + tid];
    }

    // A-frags: wave's 4 x-tiles, each load covers a contiguous 1KB
    const uint4* ap = reinterpret_cast<const uint4*>(Ppa);
    const int tile0 = xb * 16 + w * 4;
    bf16x8 af[4];
#pragma unroll
    for (int xi = 0; xi < 4; ++xi)
        af[xi] = *reinterpret_cast<const bf16x8*>(&ap[(tile0 + xi) * 64 + frag]);

    f32x4 rmax[4];
#pragma unroll
    for (int xi = 0; xi < 4; ++xi)
        rmax[xi] = (f32x4){-3.0e38f, -3.0e38f, -3.0e38f, -3.0e38f};
    float cmax[8];
#pragma unroll
    for (int yt = 0; yt < 8; ++yt) cmax[yt] = -3.0e38f;

    const f32x4 z4 = {0.0f, 0.0f, 0.0f, 0.0f};

    __syncthreads();  // Bsh ready

#pragma unroll 1
    for (int yt = 0; yt < 8; yt += 2) {
        // frag reads: byte addr = yt*1024 + kg*256 + col*16 -> 2 lanes/bank
        bf16x8 b0 = *reinterpret_cast<const bf16x8*>(&Bsh[(yt + 0) * 64 + frag]);
        bf16x8 b1 = *reinterpret_cast<const bf16x8*>(&Bsh[(yt + 1) * 64 + frag]);
#pragma unroll
        for (int xi = 0; xi < 4; ++xi) {
            f32x4 A = __builtin_amdgcn_mfma_f32_16x16x32_bf16(af[xi], b0, z4, 0, 0, 0);
            f32x4 B = __builtin_amdgcn_mfma_f32_16x16x32_bf16(af[xi], b1, z4, 0, 0, 0);
            // row-merge (pred side): lane-local, persists across whole y-loop
            rmax[xi].x = fmaxf(fmaxf(A.x, B.x), rmax[xi].x);  // v_max3
            rmax[xi].y = fmaxf(fmaxf(A.y, B.y), rmax[xi].y);
            rmax[xi].z = fmaxf(fmaxf(A.z, B.z), rmax[xi].z);
            rmax[xi].w = fmaxf(fmaxf(A.w, B.w), rmax[xi].w);
            // col-merge (gt side): lane-local over the 4 rows
            float ta = fmaxf(fmaxf(A.x, A.y), A.z);
            cmax[yt]     = fmaxf(fmaxf(ta, A.w), cmax[yt]);
            float tb = fmaxf(fmaxf(B.x, B.y), B.z);
            cmax[yt + 1] = fmaxf(fmaxf(tb, B.w), cmax[yt + 1]);
        }
    }

    // ---- row flush: ONCE per block (was per-xt in R11) ----
    // DPP ror-max over the 16 cols; col==0 lanes hold the y-chunk min.
    float* rowp = part + (size_t)yc * NPTS + xb * XCH + w * XW;
#pragma unroll
    for (int xi = 0; xi < 4; ++xi) {
#pragma unroll
        for (int c = 0; c < 4; ++c) {
            float v = rmax[xi][c];
            v = rormax<0x121>(v);
            v = rormax<0x122>(v);
            v = rormax<0x124>(v);
            v = rormax<0x128>(v);
            if (col == 0)
                rowp[xi * 16 + kg * 4 + c] = fmaxf(-2.0f * v, 0.0f);
        }
    }

    // ---- col flush: reduce 4 row-groups in-wave, then combine the 4
    // waves (they share y, split x) via LDS; coalesced slice store ----
#pragma unroll
    for (int yt = 0; yt < 8; ++yt) {
        float v = cmax[yt];
        v = fmaxf(v, __shfl_xor(v, 16, 64));
        v = fmaxf(v, __shfl_xor(v, 32, 64));
        if (kg == 0) colacc[w][yt * 16 + col] = v;
    }
    __syncthreads();
    if (tid < YCH) {
        float v = fmaxf(fmaxf(colacc[0][tid], colacc[1][tid]),
                        fmaxf(colacc[2][tid], colacc[3][tid]));
        part[(size_t)(NROWSL + xb) * NPTS + yc * YCH + tid] =
            fmaxf(-2.0f * v, 0.0f);
    }
}

__global__ __launch_bounds__(256) void chamfer_reduce(
        const float* __restrict__ part, float* __restrict__ out) {
    const int gid = blockIdx.x * 256 + threadIdx.x;  // 32 blocks x 256
    const int side = gid >> 12;                      // 4096 f32x4 per side
    const int idx4 = (gid & 4095) * 4;
    const int off  = side ? NROWSL : 0;
    const int cnt  = side ? NCOLSL : NROWSL;
    float4 m = make_float4(3.0e38f, 3.0e38f, 3.0e38f, 3.0e38f);
#pragma unroll 8
    for (int c = 0; c < cnt; ++c) {
        float4 v = *reinterpret_cast<const float4*>(
            part + (size_t)(off + c) * NPTS + idx4);
        m.x = fminf(m.x, v.x); m.y = fminf(m.y, v.y);
        m.z = fminf(m.z, v.z); m.w = fminf(m.w, v.w);
    }
    float s = sqrtf(m.x) + sqrtf(m.y) + sqrtf(m.z) + sqrtf(m.w);
#pragma unroll
    for (int o = 32; o > 0; o >>= 1)
        s += __shfl_down(s, o, 64);
    if ((threadIdx.x & 63) == 0)
        atomicAdd(out, s * (1.0f / (float)NPTS));
}

extern "C" void kernel_launch(void* const* d_in, const int* in_sizes, int n_in,
                              void* d_out, int out_size, void* d_ws, size_t ws_size,
                              hipStream_t stream) {
    const float* pred = (const float*)d_in[0];
    const float* gt   = (const float*)d_in[1];
    float* out        = (float*)d_out;
    unsigned short* Ppa = (unsigned short*)d_ws;
    unsigned short* Pgb = (unsigned short*)((char*)d_ws + WS_PGB);
    float* part         = (float*)((char*)d_ws + WS_PART);

    hipLaunchKernelGGL(pack_points, dim3(NPTS / 256), dim3(256), 0, stream,
                       pred, gt, Ppa, Pgb, out);
    hipLaunchKernelGGL(chamfer_bidi, dim3(NYC, NXB), dim3(BLOCK), 0, stream,
                       Ppa, Pgb, part);
    hipLaunchKernelGGL(chamfer_reduce, dim3(2 * NPTS / 1024), dim3(256), 0, stream,
                       part, out);
}

// Round 10
// 98.408 us; speedup vs baseline: 1.2060x; 1.2060x over previous
//
#include <hip/hip_runtime.h>

// Chamfer loss: pred (2048,8,3) vs gt (2048,8,3) fp32. N=16384 pts/side.
// out = mean(min_m d) + mean(min_n d); 8-corner group-mean == global mean.
//
// R13: minimize non-MFMA work per MFMA. R8-R12 showed a persistent ~4x
// gap between source-counted VALU and measured cycles, independent of
// flush placement -> the overhead multiplier applies to EVERYTHING that
// isn't MFMA. So: strip the kernel to its skeleton.
//  - UNIDIRECTIONAL (dir = blockIdx.z): kills cmax merges (-2 max3/MFMA),
//    shfl col-flush, colacc + its barrier. 2x MFMA count but fewer total
//    pipe cycles, and MFMA is the cheap pipe (MfmaUtil was 11%).
//  - NO LDS staging: B-frags straight from global. Packed B = 1MB/dir,
//    L2-resident (128MB L2 re-reads ~ 4us @ 34TB/s). Hot loop = 2 loads
//    + 8 MFMA + 16 v_max3. No barriers in the loop, no ds_read.
//  - wave owns af[4] (16 reg) + rmax[4] (16 reg): 256 MFMAs per wave,
//    ONE DPP flush + one coalesced store per wave. Live ~54 VGPR ->
//    spill-impossible; 2048 blocks = 8/CU = 32 waves/CU occupancy.
//  - kg-major fragment layout (R12-verified): every global load is a
//    lane-contiguous 1KB line.
//  - verified bf16 3-way-split math untouched (absmax 0.0 since R5).
// Fixed per round: 268MB ws re-poison fill ~40us + ~8us launch gaps.

#define NPTS   16384
#define BLOCK  256            // 4 waves
#define XW     64             // x-points per wave (4 tiles, af in 16 VGPR)
#define XCH    256            // x-points per block
#define NXB    (NPTS / XCH)   // 64
#define YRNG   1024           // y-points per block (64 tiles)
#define NYR    (NPTS / YRNG)  // 16
#define NTIL   (YRNG / 16)    // 64 y-tiles per range
#define ONEBF  0x3F80         // bf16 1.0

// ws: [0,4MB) packed Ppa|Ppb|Pga|Pgb (1MB each) | [4MB,6MB) part[32][NPTS]
//   slices 0..15  = pred row-min partials, id = yr
//   slices 16..31 = gt   row-min partials, id = 16+yr
#define WS_PPB  (1u << 20)
#define WS_PGA  (2u << 20)
#define WS_PGB  (3u << 20)
#define WS_PART (4u << 20)

typedef __attribute__((ext_vector_type(8))) short bf16x8;
typedef __attribute__((ext_vector_type(4))) float f32x4;

__device__ inline unsigned short f2bf(float f) {  // fp32 -> bf16 RNE
    unsigned int u = __float_as_uint(f);
    return (unsigned short)((u + 0x7FFFu + ((u >> 16) & 1u)) >> 16);
}
__device__ inline float bf2f(unsigned short h) {
    return __uint_as_float((unsigned int)h << 16);
}
__device__ inline void split3(float v, unsigned short* s) {
    unsigned short h = f2bf(v);  float r = v - bf2f(h);
    unsigned short m = f2bf(r);  r -= bf2f(m);
    s[0] = h; s[1] = m; s[2] = f2bf(r);
}

// K-slot map (identical order on A and B rows => lane->K bijection cancels):
//   s=c*3+d, c<6: cross combos (i,j)=(h,h)(h,m)(m,h)(h,l)(m,m)(l,h)
//   s=18..20: a=split3(-|p|^2/2), b=1 ; s=21..23: a=1, b=split3(-|p|^2/2)
//   s=24..31: 0   => S[r][c] = x.y - |x|^2/2 - |y|^2/2 = -d2/2
__device__ inline void build_rows(const float p[3], unsigned short* a,
                                  unsigned short* b) {
    const int CI[6] = {0, 0, 1, 0, 1, 2};
    const int CJ[6] = {0, 1, 0, 2, 1, 0};
    unsigned short xs[3][3], nn[3], t[3];
#pragma unroll
    for (int d = 0; d < 3; ++d) {
        split3(p[d], t);
        xs[0][d] = t[0]; xs[1][d] = t[1]; xs[2][d] = t[2];
    }
    split3(-0.5f * (p[0]*p[0] + p[1]*p[1] + p[2]*p[2]), nn);
#pragma unroll
    for (int c = 0; c < 6; ++c)
#pragma unroll
        for (int d = 0; d < 3; ++d) {
            a[c*3+d] = xs[CI[c]][d];
            b[c*3+d] = xs[CJ[c]][d];
        }
#pragma unroll
    for (int k = 0; k < 3; ++k) {
        a[18+k] = nn[k];  b[18+k] = ONEBF;
        a[21+k] = ONEBF;  b[21+k] = nn[k];
    }
#pragma unroll
    for (int k = 24; k < 32; ++k) { a[k] = 0; b[k] = 0; }
}

// Fragment-swizzled store (R12-verified): point i, K-chunk kg -> uint4 slot
// (i/16)*64 + kg*16 + (i%16); lane (col,kg) reads frag at slot
// tile*64 + kg*16 + col -> wave reads a contiguous 1KB line per instr.
__device__ inline void store_row_swz(uint4* dst4, int i, const unsigned short* s) {
    unsigned int w[16];
#pragma unroll
    for (int k = 0; k < 16; ++k)
        w[k] = (unsigned int)s[2*k] | ((unsigned int)s[2*k+1] << 16);
    const int base = (i >> 4) * 64 + (i & 15);
#pragma unroll
    for (int kgc = 0; kgc < 4; ++kgc)
        dst4[base + kgc * 16] = make_uint4(w[4*kgc], w[4*kgc+1],
                                           w[4*kgc+2], w[4*kgc+3]);
}

__global__ __launch_bounds__(256) void pack_points(
        const float* __restrict__ pred, const float* __restrict__ gt,
        unsigned short* __restrict__ Ppa, unsigned short* __restrict__ Ppb,
        unsigned short* __restrict__ Pga, unsigned short* __restrict__ Pgb,
        float* __restrict__ out) {
    const int i = blockIdx.x * 256 + threadIdx.x;
    if (i == 0) out[0] = 0.0f;  // replaces a memset dispatch
    if (i >= NPTS) return;
    float p[3] = {pred[3*i], pred[3*i+1], pred[3*i+2]};
    float q[3] = {gt[3*i],   gt[3*i+1],   gt[3*i+2]};
    unsigned short ra[32], rb[32];
    build_rows(p, ra, rb);
    store_row_swz(reinterpret_cast<uint4*>(Ppa), i, ra);
    store_row_swz(reinterpret_cast<uint4*>(Ppb), i, rb);
    build_rows(q, ra, rb);
    store_row_swz(reinterpret_cast<uint4*>(Pga), i, ra);
    store_row_swz(reinterpret_cast<uint4*>(Pgb), i, rb);
}

// DPP rotate-max within 16-lane rows (VALU pipe; verified R6-R12).
template <int CTRL>
__device__ inline float rormax(float v) {
    int t = __builtin_amdgcn_update_dpp(0, __float_as_int(v), CTRL, 0xF, 0xF,
                                        false);
    return fmaxf(v, __int_as_float(t));
}

__global__ __launch_bounds__(BLOCK) void chamfer_rowmin(
        const unsigned short* __restrict__ Ppa,
        const unsigned short* __restrict__ Ppb,
        const unsigned short* __restrict__ Pga,
        const unsigned short* __restrict__ Pgb,
        float* __restrict__ part) {
    const int xb  = blockIdx.x;          // fastest: blocks sharing yr adjacent
    const int yr  = blockIdx.y;
    const int dir = blockIdx.z;
    const unsigned short* __restrict__ Ap = dir ? Pga : Ppa;  // rows = X side
    const unsigned short* __restrict__ Bp = dir ? Ppb : Pgb;  // cols = Y side
    const int tid = threadIdx.x;
    const int lane = tid & 63, w = tid >> 6;
    const int col = lane & 15, kg = lane >> 4;
    const int frag = kg * 16 + col;      // uint4 index of this lane's frag

    __shared__ float rowacc[XCH];        // 1 KB epilogue buffer

    // A-frags: wave's 4 x-tiles (each load = contiguous 1KB line)
    const uint4* ap = reinterpret_cast<const uint4*>(Ap);
    const int tile0 = xb * 16 + w * 4;
    bf16x8 af[4];
#pragma unroll
    for (int xi = 0; xi < 4; ++xi)
        af[xi] = *reinterpret_cast<const bf16x8*>(&ap[(tile0 + xi) * 64 + frag]);

    f32x4 rmax[4];
#pragma unroll
    for (int xi = 0; xi < 4; ++xi)
        rmax[xi] = (f32x4){-3.0e38f, -3.0e38f, -3.0e38f, -3.0e38f};

    const f32x4 z4 = {0.0f, 0.0f, 0.0f, 0.0f};

    // hot loop: 2 global loads (L2-hit) + 8 MFMA + 16 v_max3 per step.
    // No LDS, no barriers, no flushes.
    const uint4* bp = reinterpret_cast<const uint4*>(Bp)
                      + (size_t)(yr * NTIL) * 64 + frag;
#pragma unroll 4
    for (int t = 0; t < NTIL; t += 2) {
        bf16x8 b0 = *reinterpret_cast<const bf16x8*>(&bp[(t + 0) * 64]);
        bf16x8 b1 = *reinterpret_cast<const bf16x8*>(&bp[(t + 1) * 64]);
#pragma unroll
        for (int xi = 0; xi < 4; ++xi) {
            f32x4 A = __builtin_amdgcn_mfma_f32_16x16x32_bf16(af[xi], b0, z4, 0, 0, 0);
            f32x4 B = __builtin_amdgcn_mfma_f32_16x16x32_bf16(af[xi], b1, z4, 0, 0, 0);
            rmax[xi].x = fmaxf(fmaxf(A.x, B.x), rmax[xi].x);  // v_max3
            rmax[xi].y = fmaxf(fmaxf(A.y, B.y), rmax[xi].y);
            rmax[xi].z = fmaxf(fmaxf(A.z, B.z), rmax[xi].z);
            rmax[xi].w = fmaxf(fmaxf(A.w, B.w), rmax[xi].w);
        }
    }

    // flush ONCE per wave: DPP ror-max over 16 cols, park in LDS,
    // one coalesced 1KB store per block.
#pragma unroll
    for (int xi = 0; xi < 4; ++xi) {
#pragma unroll
        for (int c = 0; c < 4; ++c) {
            float v = rmax[xi][c];
            v = rormax<0x121>(v);
            v = rormax<0x122>(v);
            v = rormax<0x124>(v);
            v = rormax<0x128>(v);
            if (col == 0)
                rowacc[w * XW + xi * 16 + kg * 4 + c] = fmaxf(-2.0f * v, 0.0f);
        }
    }
    __syncthreads();
    part[(size_t)(dir * NYR + yr) * NPTS + xb * XCH + tid] = rowacc[tid];
}

__global__ __launch_bounds__(256) void chamfer_reduce(
        const float* __restrict__ part, float* __restrict__ out) {
    const int gid = blockIdx.x * 256 + threadIdx.x;  // 32 blocks x 256
    const int side = gid >> 12;                      // 4096 f32x4 per side
    const int idx4 = (gid & 4095) * 4;
    const float* base = part + (size_t)side * NYR * NPTS + idx4;
    float4 m = make_float4(3.0e38f, 3.0e38f, 3.0e38f, 3.0e38f);
#pragma unroll
    for (int c = 0; c < NYR; ++c) {
        float4 v = *reinterpret_cast<const float4*>(base + (size_t)c * NPTS);
        m.x = fminf(m.x, v.x); m.y = fminf(m.y, v.y);
        m.z = fminf(m.z, v.z); m.w = fminf(m.w, v.w);
    }
    float s = sqrtf(m.x) + sqrtf(m.y) + sqrtf(m.z) + sqrtf(m.w);
#pragma unroll
    for (int o = 32; o > 0; o >>= 1)
        s += __shfl_down(s, o, 64);
    if ((threadIdx.x & 63) == 0)
        atomicAdd(out, s * (1.0f / (float)NPTS));
}

extern "C" void kernel_launch(void* const* d_in, const int* in_sizes, int n_in,
                              void* d_out, int out_size, void* d_ws, size_t ws_size,
                              hipStream_t stream) {
    const float* pred = (const float*)d_in[0];
    const float* gt   = (const float*)d_in[1];
    float* out        = (float*)d_out;
    unsigned short* Ppa = (unsigned short*)d_ws;
    unsigned short* Ppb = (unsigned short*)((char*)d_ws + WS_PPB);
    unsigned short* Pga = (unsigned short*)((char*)d_ws + WS_PGA);
    unsigned short* Pgb = (unsigned short*)((char*)d_ws + WS_PGB);
    float* part         = (float*)((char*)d_ws + WS_PART);

    hipLaunchKernelGGL(pack_points, dim3(NPTS / 256), dim3(256), 0, stream,
                       pred, gt, Ppa, Ppb, Pga, Pgb, out);
    hipLaunchKernelGGL(chamfer_rowmin, dim3(NXB, NYR, 2), dim3(BLOCK), 0, stream,
                       Ppa, Ppb, Pga, Pgb, part);
    hipLaunchKernelGGL(chamfer_reduce, dim3(2 * NPTS / 1024), dim3(256), 0, stream,
                       part, out);
}